// Round 13
// baseline (559.740 us; speedup 1.0000x reference)
//
#include <hip/hip_runtime.h>

#define HIDDEN 128
#define NLAYERS 4

typedef __attribute__((ext_vector_type(8))) short short8;
typedef __attribute__((ext_vector_type(4))) float f32x4;

__device__ __forceinline__ ushort f2bf(float f) {
    uint x = __builtin_bit_cast(uint, f);
    return (ushort)((x + 0x7fffu + ((x >> 16) & 1u)) >> 16);
}
__device__ __forceinline__ float bflo(uint u) {
    return __builtin_bit_cast(float, u << 16);
}
__device__ __forceinline__ float bfhi(uint u) {
    return __builtin_bit_cast(float, u & 0xffff0000u);
}

// ---------------- CSR build ----------------

__global__ void hist_kernel(const int* __restrict__ dst, int* __restrict__ counts, int E) {
    int e = blockIdx.x * blockDim.x + threadIdx.x;
    if (e < E) atomicAdd(&counts[dst[e]], 1);
}

// single-block scan, 4 elements/thread (4096/chunk)
__global__ __launch_bounds__(1024) void scan_kernel(const int* __restrict__ counts,
                                                    int* __restrict__ offsets,
                                                    int* __restrict__ wpos, int n) {
    __shared__ int wsum[16];
    __shared__ int carry_s;
    const int t = threadIdx.x, wv = t >> 6, ln = t & 63;
    if (t == 0) carry_s = 0;
    __syncthreads();
    for (int base = 0; base < n; base += 4096) {
        const int i = base + t * 4;
        int4 c = {0, 0, 0, 0};
        if (i + 3 < n) {
            c = *(const int4*)(counts + i);
        } else {
            if (i < n)     c.x = counts[i];
            if (i + 1 < n) c.y = counts[i + 1];
            if (i + 2 < n) c.z = counts[i + 2];
            if (i + 3 < n) c.w = counts[i + 3];
        }
        const int tsum = c.x + c.y + c.z + c.w;
        int s = tsum;
#pragma unroll
        for (int off = 1; off < 64; off <<= 1) {
            int x = __shfl_up(s, off, 64);
            if (ln >= off) s += x;
        }
        if (ln == 63) wsum[wv] = s;
        __syncthreads();
        if (t < 16) {
            int x = wsum[t];
#pragma unroll
            for (int off = 1; off < 16; off <<= 1) {
                int y = __shfl_up(x, off, 16);
                if ((t & 15) >= off) x += y;
            }
            wsum[t] = x;
        }
        __syncthreads();
        const int wbase = (wv ? wsum[wv - 1] : 0) + carry_s;
        const int excl = wbase + s - tsum;
        int4 o;
        o.x = excl;
        o.y = excl + c.x;
        o.z = o.y + c.y;
        o.w = o.z + c.z;
        if (i + 3 < n) {
            *(int4*)(offsets + i) = o;
            *(int4*)(wpos + i) = o;
        } else {
            if (i < n)     { offsets[i] = o.x;     wpos[i] = o.x; }
            if (i + 1 < n) { offsets[i + 1] = o.y; wpos[i + 1] = o.y; }
            if (i + 2 < n) { offsets[i + 2] = o.z; wpos[i + 2] = o.z; }
            if (i + 3 < n) { offsets[i + 3] = o.w; wpos[i + 3] = o.w; }
        }
        __syncthreads();
        if (t == 0) carry_s += wsum[15];
        __syncthreads();
    }
    if (t == 0) offsets[n] = carry_s;
}

// fill + eattr16 reorder fused: csr_src[p] = src[e]; eattr16[p][:] = bf16(edge_attr[e][:])
__global__ void fill_kernel(const int* __restrict__ src, const int* __restrict__ dst,
                            int* __restrict__ wpos, int* __restrict__ csr_src,
                            const float4* __restrict__ edge_attr,
                            ushort* __restrict__ eattr16, int E) {
    int e = blockIdx.x * blockDim.x + threadIdx.x;
    if (e < E) {
        int d = dst[e];
        int p = atomicAdd(&wpos[d], 1);
        csr_src[p] = src[e];
        float4 v0 = edge_attr[(size_t)e * 4 + 0];
        float4 v1 = edge_attr[(size_t)e * 4 + 1];
        float4 v2 = edge_attr[(size_t)e * 4 + 2];
        float4 v3 = edge_attr[(size_t)e * 4 + 3];
        uint4 q0, q1;
        q0.x = (uint)f2bf(v0.x) | ((uint)f2bf(v0.y) << 16);
        q0.y = (uint)f2bf(v0.z) | ((uint)f2bf(v0.w) << 16);
        q0.z = (uint)f2bf(v1.x) | ((uint)f2bf(v1.y) << 16);
        q0.w = (uint)f2bf(v1.z) | ((uint)f2bf(v1.w) << 16);
        q1.x = (uint)f2bf(v2.x) | ((uint)f2bf(v2.y) << 16);
        q1.y = (uint)f2bf(v2.z) | ((uint)f2bf(v2.w) << 16);
        q1.z = (uint)f2bf(v3.x) | ((uint)f2bf(v3.y) << 16);
        q1.w = (uint)f2bf(v3.z) | ((uint)f2bf(v3.w) << 16);
        ushort* op = eattr16 + (size_t)p * 16;
        *(uint4*)(op) = q0;
        *(uint4*)(op + 8) = q1;
    }
}

// ---------------- fused prep: h16init | wconv | wecolx | sentinel (region-split) ----------------
// region A [0, n*16): h16p[row][pos], pos(ch) = (ch&15)*8 + (ch>>4)
// region B: Wt[(l*2+m)][nn][kpos]; m==0 K-rows permuted
// region C: WecolX[ch][k]: k<16 -> We[k][ch]; k==16 -> be[ch]; else 0
// region D [16 threads]: h16p sentinel row n = bf16(-3.39e38) everywhere
__global__ void prep_kernel(const float* __restrict__ x, ushort* __restrict__ h16p,
                            const float* __restrict__ W1, const float* __restrict__ W2,
                            ushort* __restrict__ Wt,
                            const float* __restrict__ We, const float* __restrict__ be,
                            ushort* __restrict__ WecolX, int n) {
    int i = blockIdx.x * blockDim.x + threadIdx.x;
    const int na = n * 16;
    if (i < na) {
        int row = i >> 4, lm = i & 15;
        const float* xp = x + (size_t)row * HIDDEN + lm;
        uint4 o;
        o.x = (uint)f2bf(xp[0])  | ((uint)f2bf(xp[16]) << 16);
        o.y = (uint)f2bf(xp[32]) | ((uint)f2bf(xp[48]) << 16);
        o.z = (uint)f2bf(xp[64]) | ((uint)f2bf(xp[80]) << 16);
        o.w = (uint)f2bf(xp[96]) | ((uint)f2bf(xp[112]) << 16);
        *(uint4*)(h16p + (size_t)row * HIDDEN + lm * 8) = o;
        return;
    }
    i -= na;
    if (i < NLAYERS * 2 * HIDDEN * HIDDEN) {
        int l = i >> 15;
        int m = (i >> 14) & 1;
        int nn = (i >> 7) & 127;
        int kpos = i & 127;
        int kk = (m == 0) ? (((kpos & 7) << 4) | (kpos >> 3)) : kpos;
        const float* W = m ? W2 : W1;
        Wt[i] = f2bf(W[l * 16384 + kk * 128 + nn]);
        return;
    }
    i -= NLAYERS * 2 * HIDDEN * HIDDEN;
    if (i < 128 * 32) {
        int ch = i >> 5, k = i & 31;
        float v = (k < 16) ? We[k * HIDDEN + ch] : ((k == 16) ? be[ch] : 0.f);
        WecolX[i] = f2bf(v);
        return;
    }
    i -= 128 * 32;
    if (i < 16) {
        uint4 s = {0xFF7FFF7Fu, 0xFF7FFF7Fu, 0xFF7FFF7Fu, 0xFF7FFF7Fu};
        *(uint4*)(h16p + (size_t)n * HIDDEN + i * 8) = s;
    }
}

// ---------------- aggregation: MFMA ea recompute, 1-deep chunk pipeline, sentinel mask ----------------
// wave = node (2 reps); per 16-edge chunk:
//   A: rows=edges, K0-15=feats, K16=1.0 (lg==2 literal) -> be folded via B row 16 (WecolX)
//   B: resident frags (32 VGPR), loaded once per wave
//   gathers for invalid slots hit sentinel row n (-3.4e38) -> relu contributes exact 0
//   next chunk's loads issued before current chunk's MFMA/accumulate (latency hiding)
__global__ __launch_bounds__(256) void agg_kernel(const ushort* __restrict__ h16p,
                                                  const int* __restrict__ csr_src,
                                                  const ushort* __restrict__ eattr16,
                                                  const int* __restrict__ offsets,
                                                  const ushort* __restrict__ WecolX,
                                                  ushort* __restrict__ z0p, int n) {
    const int w = threadIdx.x >> 6, l = threadIdx.x & 63;
    const int lm = l & 15, lg = l >> 4;

    // resident B-frags: lane covers K slots lg*8..+8 of channel nt*16+lm
    short8 bfr[8];
#pragma unroll
    for (int nt = 0; nt < 8; ++nt)
        bfr[nt] = *(const short8*)(WecolX + (size_t)(nt * 16 + lm) * 32 + lg * 8);

    for (int rep = 0; rep < 2; ++rep) {
        const int v = blockIdx.x * 8 + w + rep * 4;
        if (v >= n) continue;

        const int e0 = offsets[v], e1 = offsets[v + 1];
        float acc[8];
#pragma unroll
        for (int i = 0; i < 8; ++i) acc[i] = 0.f;

        auto loadchunk = [&](int B, short8& af_, uint4* hv_) {
            if (lg < 2) {
                int ae = B + lm;
                if (ae >= e1) ae = e1 - 1;
                af_ = *(const short8*)(eattr16 + (size_t)ae * 16 + lg * 8);
            } else if (lg == 2) {
                af_ = short8{(short)0x3F80, 0, 0, 0, 0, 0, 0, 0};
            } else {
                af_ = short8{0, 0, 0, 0, 0, 0, 0, 0};
            }
#pragma unroll
            for (int j = 0; j < 4; ++j) {
                int e = B + lg * 4 + j;
                int ec = (e < e1) ? e : (e1 - 1);
                int s = csr_src[ec];
                s = (e < e1) ? s : n;   // sentinel row for padded slots
                hv_[j] = *(const uint4*)(h16p + (size_t)s * HIDDEN + lm * 8);
            }
        };

        short8 afc;
        uint4 hvc[4];
        if (e0 < e1) loadchunk(e0, afc, hvc);

        for (int B = e0; B < e1; B += 16) {
            short8 afn;
            uint4 hvn[4];
            const bool more = (B + 16) < e1;     // wave-uniform
            if (more) loadchunk(B + 16, afn, hvn);

            // compute current chunk: 8 channel tiles
#pragma unroll
            for (int nt = 0; nt < 8; ++nt) {
                f32x4 c = {0.f, 0.f, 0.f, 0.f};
                f32x4 d = __builtin_amdgcn_mfma_f32_16x16x32_bf16(afc, bfr[nt], c, 0, 0, 0);
#pragma unroll
                for (int j = 0; j < 4; ++j) {
                    uint word = (nt < 2) ? hvc[j].x : (nt < 4) ? hvc[j].y
                              : (nt < 6) ? hvc[j].z : hvc[j].w;
                    float hc = (nt & 1) ? bfhi(word) : bflo(word);
                    acc[nt] += fmaxf(d[j] + hc, 0.f);
                }
            }

            if (more) {
                afc = afn;
#pragma unroll
                for (int j = 0; j < 4; ++j) hvc[j] = hvn[j];
            }
        }

        // reduce across the 4 groups
#pragma unroll
        for (int i = 0; i < 8; ++i) {
            acc[i] += __shfl_xor(acc[i], 16, 64);
            acc[i] += __shfl_xor(acc[i], 32, 64);
        }

        if (lg == 0) {
            // self term from h16p (bf16 h), same permuted positions
            const uint4 sv = *(const uint4*)(h16p + (size_t)v * HIDDEN + lm * 8);
            uint4 o;
            o.x = (uint)f2bf(bflo(sv.x) + acc[0]) | ((uint)f2bf(bfhi(sv.x) + acc[1]) << 16);
            o.y = (uint)f2bf(bflo(sv.y) + acc[2]) | ((uint)f2bf(bfhi(sv.y) + acc[3]) << 16);
            o.z = (uint)f2bf(bflo(sv.z) + acc[4]) | ((uint)f2bf(bfhi(sv.z) + acc[5]) << 16);
            o.w = (uint)f2bf(bflo(sv.w) + acc[6]) | ((uint)f2bf(bfhi(sv.w) + acc[7]) << 16);
            *(uint4*)(z0p + (size_t)v * HIDDEN + lm * 8) = o;
        }
    }
}

// ---------------- fused MFMA MLP + in-register LayerNorm + bf16 residual ----------------
// z0p/h16p are channel-permuted; W1t has matching K-permutation.
// last==0: h16p <- bf16(relu(LN) + h16p). last==1: h32 <- relu(LN) + h16p (canonical layout).
__global__ __launch_bounds__(256, 3) void mlp_kernel(const ushort* __restrict__ z0p,
                                                     ushort* __restrict__ h16p,
                                                     float* __restrict__ h32,
                                                     const ushort* __restrict__ W1t,
                                                     const ushort* __restrict__ W2t,
                                                     const float* __restrict__ b1,
                                                     const float* __restrict__ b2,
                                                     const float* __restrict__ lng,
                                                     const float* __restrict__ lnb,
                                                     int n, int last) {
    __shared__ char smem[49152];  // [0,32K): weights (swizzled bf16) ; [32K,48K): act
    const int t = threadIdx.x, l = t & 63, w = t >> 6;
    const int lm = l & 15, lg = l >> 4;
    const int r0 = blockIdx.x * 64;

#pragma unroll
    for (int j = 0; j < 8; ++j) {
        int idx = t + j * 256;
        int byte = (idx * 16) ^ (((idx >> 4) & 7) << 4);
        *(short8*)(smem + byte) = *(const short8*)(W1t + idx * 8);
    }

    float b1v[8], b2v[8], lngv[8], lnbv[8];
#pragma unroll
    for (int nt = 0; nt < 8; ++nt) {
        int col = nt * 16 + lm;
        b1v[nt] = b1[col]; b2v[nt] = b2[col];
        lngv[nt] = lng[col]; lnbv[nt] = lnb[col];
    }

    short8 a[4];
    {
        int arow = r0 + w * 16 + lm;
        if (arow >= n) arow = n - 1;
        const ushort* zp = z0p + (size_t)arow * HIDDEN + lg * 8;
#pragma unroll
        for (int kk = 0; kk < 4; ++kk) a[kk] = *(const short8*)(zp + kk * 32);
    }
    __syncthreads();

    f32x4 acc[8];
#pragma unroll
    for (int nt = 0; nt < 8; ++nt) {
        f32x4 c = {0.f, 0.f, 0.f, 0.f};
#pragma unroll
        for (int kk = 0; kk < 4; ++kk) {
            int nrow = nt * 16 + lm;
            int byte = (nrow * 256 + kk * 64 + lg * 16) ^ ((nrow & 7) << 4);
            short8 b = *(const short8*)(smem + byte);
            c = __builtin_amdgcn_mfma_f32_16x16x32_bf16(a[kk], b, c, 0, 0, 0);
        }
        acc[nt] = c;
    }

#pragma unroll
    for (int nt = 0; nt < 8; ++nt) {
        int col = nt * 16 + lm;
#pragma unroll
        for (int j = 0; j < 4; ++j) {
            int rw = w * 16 + lg * 4 + j;
            int byte = (rw * 256 + col * 2) ^ ((rw & 7) << 4);
            *(ushort*)(smem + 32768 + byte) = f2bf(fmaxf(acc[nt][j] + b1v[nt], 0.f));
        }
    }
    __syncthreads();

#pragma unroll
    for (int j = 0; j < 8; ++j) {
        int idx = t + j * 256;
        int byte = (idx * 16) ^ (((idx >> 4) & 7) << 4);
        *(short8*)(smem + byte) = *(const short8*)(W2t + idx * 8);
    }
    short8 a2[4];
    {
        int rw = w * 16 + lm;
#pragma unroll
        for (int kk = 0; kk < 4; ++kk) {
            int byte = (rw * 256 + kk * 64 + lg * 16) ^ ((rw & 7) << 4);
            a2[kk] = *(const short8*)(smem + 32768 + byte);
        }
    }
    __syncthreads();

    f32x4 acc2[8];
#pragma unroll
    for (int nt = 0; nt < 8; ++nt) {
        f32x4 c = {0.f, 0.f, 0.f, 0.f};
#pragma unroll
        for (int kk = 0; kk < 4; ++kk) {
            int nrow = nt * 16 + lm;
            int byte = (nrow * 256 + kk * 64 + lg * 16) ^ ((nrow & 7) << 4);
            short8 b = *(const short8*)(smem + byte);
            c = __builtin_amdgcn_mfma_f32_16x16x32_bf16(a2[kk], b, c, 0, 0, 0);
        }
        acc2[nt] = c;
    }

    float val[8][4];
#pragma unroll
    for (int nt = 0; nt < 8; ++nt)
#pragma unroll
        for (int j = 0; j < 4; ++j) val[nt][j] = acc2[nt][j] + b2v[nt];

    float mu[4], rs[4];
#pragma unroll
    for (int j = 0; j < 4; ++j) {
        float s = 0.f;
#pragma unroll
        for (int nt = 0; nt < 8; ++nt) s += val[nt][j];
        s += __shfl_xor(s, 1, 64); s += __shfl_xor(s, 2, 64);
        s += __shfl_xor(s, 4, 64); s += __shfl_xor(s, 8, 64);
        mu[j] = s * (1.f / 128.f);
        float d2 = 0.f;
#pragma unroll
        for (int nt = 0; nt < 8; ++nt) {
            float d = val[nt][j] - mu[j];
            d2 = fmaf(d, d, d2);
        }
        d2 += __shfl_xor(d2, 1, 64); d2 += __shfl_xor(d2, 2, 64);
        d2 += __shfl_xor(d2, 4, 64); d2 += __shfl_xor(d2, 8, 64);
        rs[j] = rsqrtf(d2 * (1.f / 128.f) + 1e-5f);
    }

#pragma unroll
    for (int j = 0; j < 4; ++j) {
        int grow = r0 + w * 16 + lg * 4 + j;
        if (grow < n) {
            const uint4 hvv = *(const uint4*)(h16p + (size_t)grow * HIDDEN + lm * 8);
            float hc[8] = {bflo(hvv.x), bfhi(hvv.x), bflo(hvv.y), bfhi(hvv.y),
                           bflo(hvv.z), bfhi(hvv.z), bflo(hvv.w), bfhi(hvv.w)};
            float y[8];
#pragma unroll
            for (int nt = 0; nt < 8; ++nt)
                y[nt] = fmaxf((val[nt][j] - mu[j]) * rs[j] * lngv[nt] + lnbv[nt], 0.f) + hc[nt];
            if (last) {
#pragma unroll
                for (int nt = 0; nt < 8; ++nt)
                    h32[(size_t)grow * HIDDEN + nt * 16 + lm] = y[nt];
            } else {
                uint4 o4;
                o4.x = (uint)f2bf(y[0]) | ((uint)f2bf(y[1]) << 16);
                o4.y = (uint)f2bf(y[2]) | ((uint)f2bf(y[3]) << 16);
                o4.z = (uint)f2bf(y[4]) | ((uint)f2bf(y[5]) << 16);
                o4.w = (uint)f2bf(y[6]) | ((uint)f2bf(y[7]) << 16);
                *(uint4*)(h16p + (size_t)grow * HIDDEN + lm * 8) = o4;
            }
        }
    }
}

// ---------------- launch ----------------

extern "C" void kernel_launch(void* const* d_in, const int* in_sizes, int n_in,
                              void* d_out, int out_size, void* d_ws, size_t ws_size,
                              hipStream_t stream) {
    const float* x     = (const float*)d_in[0];
    const int*   ei    = (const int*)d_in[2];
    const float* eattr = (const float*)d_in[3];
    const float* We    = (const float*)d_in[4];
    const float* be    = (const float*)d_in[5];
    const float* W1    = (const float*)d_in[6];
    const float* b1    = (const float*)d_in[7];
    const float* W2    = (const float*)d_in[8];
    const float* b2    = (const float*)d_in[9];
    const float* lng   = (const float*)d_in[10];
    const float* lnb   = (const float*)d_in[11];
    float* h32 = (float*)d_out;

    const int n = in_sizes[0] / HIDDEN;
    const int E = in_sizes[2] / 2;
    const int* src = ei;
    const int* dst = ei + E;

    size_t off = 0;
    auto take = [&](size_t bytes) {
        void* p = (char*)d_ws + off;
        off += (bytes + 255) & ~(size_t)255;
        return p;
    };
    ushort* z0p     = (ushort*)take((size_t)n * HIDDEN * 2);
    ushort* h16p    = (ushort*)take((size_t)(n + 1) * HIDDEN * 2);   // +1 sentinel row
    ushort* Wt      = (ushort*)take((size_t)NLAYERS * 2 * HIDDEN * HIDDEN * 2);
    ushort* WecolX  = (ushort*)take((size_t)HIDDEN * 32 * 2);
    int*    counts  = (int*)take((size_t)n * 4);
    int*    offsets = (int*)take(((size_t)n + 1) * 4);
    int*    wpos    = (int*)take((size_t)n * 4);
    int*    csr_src = (int*)take((size_t)E * 4);
    ushort* eattr16 = (ushort*)take((size_t)E * 16 * 2);

    const int prep_total = n * 16 + NLAYERS * 2 * HIDDEN * HIDDEN + 128 * 32 + 16;
    prep_kernel<<<(prep_total + 255) / 256, 256, 0, stream>>>(x, h16p, W1, W2, Wt,
                                                              We, be, WecolX, n);

    hipMemsetAsync(counts, 0, (size_t)n * 4, stream);
    int eb = (E + 255) / 256;
    hist_kernel<<<eb, 256, 0, stream>>>(dst, counts, E);
    scan_kernel<<<1, 1024, 0, stream>>>(counts, offsets, wpos, n);
    fill_kernel<<<eb, 256, 0, stream>>>(src, dst, wpos, csr_src,
                                        (const float4*)eattr, eattr16, E);

    for (int lyr = 0; lyr < NLAYERS; ++lyr) {
        agg_kernel<<<(n + 7) / 8, 256, 0, stream>>>(h16p, csr_src, eattr16, offsets,
                                                    WecolX, z0p, n);
        mlp_kernel<<<(n + 63) / 64, 256, 0, stream>>>(z0p, h16p, h32,
                                                      Wt + (size_t)(lyr * 2 + 0) * 16384,
                                                      Wt + (size_t)(lyr * 2 + 1) * 16384,
                                                      b1 + (size_t)lyr * HIDDEN,
                                                      b2 + (size_t)lyr * HIDDEN,
                                                      lng + (size_t)lyr * HIDDEN,
                                                      lnb + (size_t)lyr * HIDDEN,
                                                      n, lyr == NLAYERS - 1);
    }
}

// Round 14
// 400.739 us; speedup vs baseline: 1.3968x; 1.3968x over previous
//
#include <hip/hip_runtime.h>

#define HIDDEN 128
#define NLAYERS 4

typedef __attribute__((ext_vector_type(8))) short short8;
typedef __attribute__((ext_vector_type(4))) float f32x4;

__device__ __forceinline__ ushort f2bf(float f) {
    uint x = __builtin_bit_cast(uint, f);
    return (ushort)((x + 0x7fffu + ((x >> 16) & 1u)) >> 16);
}
__device__ __forceinline__ float bflo(uint u) {
    return __builtin_bit_cast(float, u << 16);
}
__device__ __forceinline__ float bfhi(uint u) {
    return __builtin_bit_cast(float, u & 0xffff0000u);
}

// ---------------- CSR build ----------------

__global__ void hist_kernel(const int* __restrict__ dst, int* __restrict__ counts, int E) {
    int e = blockIdx.x * blockDim.x + threadIdx.x;
    if (e < E) atomicAdd(&counts[dst[e]], 1);
}

// single-block scan, 4 elements/thread (4096/chunk)
__global__ __launch_bounds__(1024) void scan_kernel(const int* __restrict__ counts,
                                                    int* __restrict__ offsets,
                                                    int* __restrict__ wpos, int n) {
    __shared__ int wsum[16];
    __shared__ int carry_s;
    const int t = threadIdx.x, wv = t >> 6, ln = t & 63;
    if (t == 0) carry_s = 0;
    __syncthreads();
    for (int base = 0; base < n; base += 4096) {
        const int i = base + t * 4;
        int4 c = {0, 0, 0, 0};
        if (i + 3 < n) {
            c = *(const int4*)(counts + i);
        } else {
            if (i < n)     c.x = counts[i];
            if (i + 1 < n) c.y = counts[i + 1];
            if (i + 2 < n) c.z = counts[i + 2];
            if (i + 3 < n) c.w = counts[i + 3];
        }
        const int tsum = c.x + c.y + c.z + c.w;
        int s = tsum;
#pragma unroll
        for (int off = 1; off < 64; off <<= 1) {
            int x = __shfl_up(s, off, 64);
            if (ln >= off) s += x;
        }
        if (ln == 63) wsum[wv] = s;
        __syncthreads();
        if (t < 16) {
            int x = wsum[t];
#pragma unroll
            for (int off = 1; off < 16; off <<= 1) {
                int y = __shfl_up(x, off, 16);
                if ((t & 15) >= off) x += y;
            }
            wsum[t] = x;
        }
        __syncthreads();
        const int wbase = (wv ? wsum[wv - 1] : 0) + carry_s;
        const int excl = wbase + s - tsum;
        int4 o;
        o.x = excl;
        o.y = excl + c.x;
        o.z = o.y + c.y;
        o.w = o.z + c.z;
        if (i + 3 < n) {
            *(int4*)(offsets + i) = o;
            *(int4*)(wpos + i) = o;
        } else {
            if (i < n)     { offsets[i] = o.x;     wpos[i] = o.x; }
            if (i + 1 < n) { offsets[i + 1] = o.y; wpos[i + 1] = o.y; }
            if (i + 2 < n) { offsets[i + 2] = o.z; wpos[i + 2] = o.z; }
            if (i + 3 < n) { offsets[i + 3] = o.w; wpos[i + 3] = o.w; }
        }
        __syncthreads();
        if (t == 0) carry_s += wsum[15];
        __syncthreads();
    }
    if (t == 0) offsets[n] = carry_s;
}

// fill + eattr16 reorder fused: csr_src[p] = src[e]; eattr16[p][:] = bf16(edge_attr[e][:])
__global__ void fill_kernel(const int* __restrict__ src, const int* __restrict__ dst,
                            int* __restrict__ wpos, int* __restrict__ csr_src,
                            const float4* __restrict__ edge_attr,
                            ushort* __restrict__ eattr16, int E) {
    int e = blockIdx.x * blockDim.x + threadIdx.x;
    if (e < E) {
        int d = dst[e];
        int p = atomicAdd(&wpos[d], 1);
        csr_src[p] = src[e];
        float4 v0 = edge_attr[(size_t)e * 4 + 0];
        float4 v1 = edge_attr[(size_t)e * 4 + 1];
        float4 v2 = edge_attr[(size_t)e * 4 + 2];
        float4 v3 = edge_attr[(size_t)e * 4 + 3];
        uint4 q0, q1;
        q0.x = (uint)f2bf(v0.x) | ((uint)f2bf(v0.y) << 16);
        q0.y = (uint)f2bf(v0.z) | ((uint)f2bf(v0.w) << 16);
        q0.z = (uint)f2bf(v1.x) | ((uint)f2bf(v1.y) << 16);
        q0.w = (uint)f2bf(v1.z) | ((uint)f2bf(v1.w) << 16);
        q1.x = (uint)f2bf(v2.x) | ((uint)f2bf(v2.y) << 16);
        q1.y = (uint)f2bf(v2.z) | ((uint)f2bf(v2.w) << 16);
        q1.z = (uint)f2bf(v3.x) | ((uint)f2bf(v3.y) << 16);
        q1.w = (uint)f2bf(v3.z) | ((uint)f2bf(v3.w) << 16);
        ushort* op = eattr16 + (size_t)p * 16;
        *(uint4*)(op) = q0;
        *(uint4*)(op + 8) = q1;
    }
}

// ---------------- fused prep: h16init | wconv | wecolx | sentinel (region-split) ----------------
// region A [0, n*16): h16p[row][pos], pos(ch) = (ch&15)*8 + (ch>>4)
// region B: Wt[(l*2+m)][nn][kpos]; m==0 K-rows permuted
// region C: WecolX[ch][k]: k<16 -> We[k][ch]; k==16 -> be[ch]; else 0
// region D [16 threads]: h16p sentinel row n = bf16(-3.39e38) everywhere
__global__ void prep_kernel(const float* __restrict__ x, ushort* __restrict__ h16p,
                            const float* __restrict__ W1, const float* __restrict__ W2,
                            ushort* __restrict__ Wt,
                            const float* __restrict__ We, const float* __restrict__ be,
                            ushort* __restrict__ WecolX, int n) {
    int i = blockIdx.x * blockDim.x + threadIdx.x;
    const int na = n * 16;
    if (i < na) {
        int row = i >> 4, lm = i & 15;
        const float* xp = x + (size_t)row * HIDDEN + lm;
        uint4 o;
        o.x = (uint)f2bf(xp[0])  | ((uint)f2bf(xp[16]) << 16);
        o.y = (uint)f2bf(xp[32]) | ((uint)f2bf(xp[48]) << 16);
        o.z = (uint)f2bf(xp[64]) | ((uint)f2bf(xp[80]) << 16);
        o.w = (uint)f2bf(xp[96]) | ((uint)f2bf(xp[112]) << 16);
        *(uint4*)(h16p + (size_t)row * HIDDEN + lm * 8) = o;
        return;
    }
    i -= na;
    if (i < NLAYERS * 2 * HIDDEN * HIDDEN) {
        int l = i >> 15;
        int m = (i >> 14) & 1;
        int nn = (i >> 7) & 127;
        int kpos = i & 127;
        int kk = (m == 0) ? (((kpos & 7) << 4) | (kpos >> 3)) : kpos;
        const float* W = m ? W2 : W1;
        Wt[i] = f2bf(W[l * 16384 + kk * 128 + nn]);
        return;
    }
    i -= NLAYERS * 2 * HIDDEN * HIDDEN;
    if (i < 128 * 32) {
        int ch = i >> 5, k = i & 31;
        float v = (k < 16) ? We[k * HIDDEN + ch] : ((k == 16) ? be[ch] : 0.f);
        WecolX[i] = f2bf(v);
        return;
    }
    i -= 128 * 32;
    if (i < 16) {
        uint4 s = {0xFF7FFF7Fu, 0xFF7FFF7Fu, 0xFF7FFF7Fu, 0xFF7FFF7Fu};
        *(uint4*)(h16p + (size_t)n * HIDDEN + i * 8) = s;
    }
}

// ---------------- aggregation: MFMA ea recompute, zero LDS, 2 nodes/wave, sentinel mask ----------------
// per 16-edge chunk:
//   A: rows=edges, K0-15=feats, K16=1.0 (lg==2 literal) -> be folded via B row 16 (WecolX)
//   B: resident frags (32 VGPR), loaded once per wave (amortized over 2 nodes)
//   gathers for invalid slots hit sentinel row n (-3.4e38) -> relu contributes exact 0
//   D lane (lm,lg): edges lg*4+j, channels {nt*16+lm} == h16p gather positions lm*8+nt
__global__ __launch_bounds__(256) void agg_kernel(const ushort* __restrict__ h16p,
                                                  const int* __restrict__ csr_src,
                                                  const ushort* __restrict__ eattr16,
                                                  const int* __restrict__ offsets,
                                                  const ushort* __restrict__ WecolX,
                                                  ushort* __restrict__ z0p, int n) {
    const int w = threadIdx.x >> 6, l = threadIdx.x & 63;
    const int lm = l & 15, lg = l >> 4;

    // resident B-frags: lane covers K slots lg*8..+8 of channel nt*16+lm
    short8 bfr[8];
#pragma unroll
    for (int nt = 0; nt < 8; ++nt)
        bfr[nt] = *(const short8*)(WecolX + (size_t)(nt * 16 + lm) * 32 + lg * 8);

    for (int rep = 0; rep < 2; ++rep) {
        const int v = blockIdx.x * 8 + w + rep * 4;
        if (v >= n) continue;

        const int e0 = offsets[v], e1 = offsets[v + 1];
        float acc[8];
#pragma unroll
        for (int i = 0; i < 8; ++i) acc[i] = 0.f;

        for (int B = e0; B < e1; B += 16) {
            // A-frag: lg<2 = edge feats; lg==2 = {1.0,...} (bias row); lg==3 = 0
            short8 af;
            if (lg < 2) {
                int ae = B + lm;
                if (ae >= e1) ae = e1 - 1;
                af = *(const short8*)(eattr16 + (size_t)ae * 16 + lg * 8);
            } else if (lg == 2) {
                af = short8{(short)0x3F80, 0, 0, 0, 0, 0, 0, 0};
            } else {
                af = short8{0, 0, 0, 0, 0, 0, 0, 0};
            }

            // my group's 4 edges: src (sentinel row for padded slots) + gathers
            int sj[4];
#pragma unroll
            for (int j = 0; j < 4; ++j) {
                int e = B + lg * 4 + j;
                int ec = (e < e1) ? e : (e1 - 1);
                int s = csr_src[ec];
                sj[j] = (e < e1) ? s : n;
            }
            uint4 hv[4];
#pragma unroll
            for (int j = 0; j < 4; ++j)
                hv[j] = *(const uint4*)(h16p + (size_t)sj[j] * HIDDEN + lm * 8);

            // 8 channel tiles
#pragma unroll
            for (int nt = 0; nt < 8; ++nt) {
                f32x4 c = {0.f, 0.f, 0.f, 0.f};
                f32x4 d = __builtin_amdgcn_mfma_f32_16x16x32_bf16(af, bfr[nt], c, 0, 0, 0);
#pragma unroll
                for (int j = 0; j < 4; ++j) {
                    uint word = (nt < 2) ? hv[j].x : (nt < 4) ? hv[j].y
                              : (nt < 6) ? hv[j].z : hv[j].w;
                    float hc = (nt & 1) ? bfhi(word) : bflo(word);
                    acc[nt] += fmaxf(d[j] + hc, 0.f);
                }
            }
        }

        // reduce across the 4 groups
#pragma unroll
        for (int i = 0; i < 8; ++i) {
            acc[i] += __shfl_xor(acc[i], 16, 64);
            acc[i] += __shfl_xor(acc[i], 32, 64);
        }

        if (lg == 0) {
            // self term from h16p (bf16 h), same permuted positions
            const uint4 sv = *(const uint4*)(h16p + (size_t)v * HIDDEN + lm * 8);
            uint4 o;
            o.x = (uint)f2bf(bflo(sv.x) + acc[0]) | ((uint)f2bf(bfhi(sv.x) + acc[1]) << 16);
            o.y = (uint)f2bf(bflo(sv.y) + acc[2]) | ((uint)f2bf(bfhi(sv.y) + acc[3]) << 16);
            o.z = (uint)f2bf(bflo(sv.z) + acc[4]) | ((uint)f2bf(bfhi(sv.z) + acc[5]) << 16);
            o.w = (uint)f2bf(bflo(sv.w) + acc[6]) | ((uint)f2bf(bfhi(sv.w) + acc[7]) << 16);
            *(uint4*)(z0p + (size_t)v * HIDDEN + lm * 8) = o;
        }
    }
}

// ---------------- fused MFMA MLP + in-register LayerNorm + bf16 residual ----------------
// z0p/h16p are channel-permuted; W1t has matching K-permutation.
// last==0: h16p <- bf16(relu(LN) + h16p). last==1: h32 <- relu(LN) + h16p (canonical layout).
__global__ __launch_bounds__(256, 3) void mlp_kernel(const ushort* __restrict__ z0p,
                                                     ushort* __restrict__ h16p,
                                                     float* __restrict__ h32,
                                                     const ushort* __restrict__ W1t,
                                                     const ushort* __restrict__ W2t,
                                                     const float* __restrict__ b1,
                                                     const float* __restrict__ b2,
                                                     const float* __restrict__ lng,
                                                     const float* __restrict__ lnb,
                                                     int n, int last) {
    __shared__ char smem[49152];  // [0,32K): weights (swizzled bf16) ; [32K,48K): act
    const int t = threadIdx.x, l = t & 63, w = t >> 6;
    const int lm = l & 15, lg = l >> 4;
    const int r0 = blockIdx.x * 64;

#pragma unroll
    for (int j = 0; j < 8; ++j) {
        int idx = t + j * 256;
        int byte = (idx * 16) ^ (((idx >> 4) & 7) << 4);
        *(short8*)(smem + byte) = *(const short8*)(W1t + idx * 8);
    }

    float b1v[8], b2v[8], lngv[8], lnbv[8];
#pragma unroll
    for (int nt = 0; nt < 8; ++nt) {
        int col = nt * 16 + lm;
        b1v[nt] = b1[col]; b2v[nt] = b2[col];
        lngv[nt] = lng[col]; lnbv[nt] = lnb[col];
    }

    short8 a[4];
    {
        int arow = r0 + w * 16 + lm;
        if (arow >= n) arow = n - 1;
        const ushort* zp = z0p + (size_t)arow * HIDDEN + lg * 8;
#pragma unroll
        for (int kk = 0; kk < 4; ++kk) a[kk] = *(const short8*)(zp + kk * 32);
    }
    __syncthreads();

    f32x4 acc[8];
#pragma unroll
    for (int nt = 0; nt < 8; ++nt) {
        f32x4 c = {0.f, 0.f, 0.f, 0.f};
#pragma unroll
        for (int kk = 0; kk < 4; ++kk) {
            int nrow = nt * 16 + lm;
            int byte = (nrow * 256 + kk * 64 + lg * 16) ^ ((nrow & 7) << 4);
            short8 b = *(const short8*)(smem + byte);
            c = __builtin_amdgcn_mfma_f32_16x16x32_bf16(a[kk], b, c, 0, 0, 0);
        }
        acc[nt] = c;
    }

#pragma unroll
    for (int nt = 0; nt < 8; ++nt) {
        int col = nt * 16 + lm;
#pragma unroll
        for (int j = 0; j < 4; ++j) {
            int rw = w * 16 + lg * 4 + j;
            int byte = (rw * 256 + col * 2) ^ ((rw & 7) << 4);
            *(ushort*)(smem + 32768 + byte) = f2bf(fmaxf(acc[nt][j] + b1v[nt], 0.f));
        }
    }
    __syncthreads();

#pragma unroll
    for (int j = 0; j < 8; ++j) {
        int idx = t + j * 256;
        int byte = (idx * 16) ^ (((idx >> 4) & 7) << 4);
        *(short8*)(smem + byte) = *(const short8*)(W2t + idx * 8);
    }
    short8 a2[4];
    {
        int rw = w * 16 + lm;
#pragma unroll
        for (int kk = 0; kk < 4; ++kk) {
            int byte = (rw * 256 + kk * 64 + lg * 16) ^ ((rw & 7) << 4);
            a2[kk] = *(const short8*)(smem + 32768 + byte);
        }
    }
    __syncthreads();

    f32x4 acc2[8];
#pragma unroll
    for (int nt = 0; nt < 8; ++nt) {
        f32x4 c = {0.f, 0.f, 0.f, 0.f};
#pragma unroll
        for (int kk = 0; kk < 4; ++kk) {
            int nrow = nt * 16 + lm;
            int byte = (nrow * 256 + kk * 64 + lg * 16) ^ ((nrow & 7) << 4);
            short8 b = *(const short8*)(smem + byte);
            c = __builtin_amdgcn_mfma_f32_16x16x32_bf16(a2[kk], b, c, 0, 0, 0);
        }
        acc2[nt] = c;
    }

    float val[8][4];
#pragma unroll
    for (int nt = 0; nt < 8; ++nt)
#pragma unroll
        for (int j = 0; j < 4; ++j) val[nt][j] = acc2[nt][j] + b2v[nt];

    float mu[4], rs[4];
#pragma unroll
    for (int j = 0; j < 4; ++j) {
        float s = 0.f;
#pragma unroll
        for (int nt = 0; nt < 8; ++nt) s += val[nt][j];
        s += __shfl_xor(s, 1, 64); s += __shfl_xor(s, 2, 64);
        s += __shfl_xor(s, 4, 64); s += __shfl_xor(s, 8, 64);
        mu[j] = s * (1.f / 128.f);
        float d2 = 0.f;
#pragma unroll
        for (int nt = 0; nt < 8; ++nt) {
            float d = val[nt][j] - mu[j];
            d2 = fmaf(d, d, d2);
        }
        d2 += __shfl_xor(d2, 1, 64); d2 += __shfl_xor(d2, 2, 64);
        d2 += __shfl_xor(d2, 4, 64); d2 += __shfl_xor(d2, 8, 64);
        rs[j] = rsqrtf(d2 * (1.f / 128.f) + 1e-5f);
    }

#pragma unroll
    for (int j = 0; j < 4; ++j) {
        int grow = r0 + w * 16 + lg * 4 + j;
        if (grow < n) {
            const uint4 hvv = *(const uint4*)(h16p + (size_t)grow * HIDDEN + lm * 8);
            float hc[8] = {bflo(hvv.x), bfhi(hvv.x), bflo(hvv.y), bfhi(hvv.y),
                           bflo(hvv.z), bfhi(hvv.z), bflo(hvv.w), bfhi(hvv.w)};
            float y[8];
#pragma unroll
            for (int nt = 0; nt < 8; ++nt)
                y[nt] = fmaxf((val[nt][j] - mu[j]) * rs[j] * lngv[nt] + lnbv[nt], 0.f) + hc[nt];
            if (last) {
#pragma unroll
                for (int nt = 0; nt < 8; ++nt)
                    h32[(size_t)grow * HIDDEN + nt * 16 + lm] = y[nt];
            } else {
                uint4 o4;
                o4.x = (uint)f2bf(y[0]) | ((uint)f2bf(y[1]) << 16);
                o4.y = (uint)f2bf(y[2]) | ((uint)f2bf(y[3]) << 16);
                o4.z = (uint)f2bf(y[4]) | ((uint)f2bf(y[5]) << 16);
                o4.w = (uint)f2bf(y[6]) | ((uint)f2bf(y[7]) << 16);
                *(uint4*)(h16p + (size_t)grow * HIDDEN + lm * 8) = o4;
            }
        }
    }
}

// ---------------- launch ----------------

extern "C" void kernel_launch(void* const* d_in, const int* in_sizes, int n_in,
                              void* d_out, int out_size, void* d_ws, size_t ws_size,
                              hipStream_t stream) {
    const float* x     = (const float*)d_in[0];
    const int*   ei    = (const int*)d_in[2];
    const float* eattr = (const float*)d_in[3];
    const float* We    = (const float*)d_in[4];
    const float* be    = (const float*)d_in[5];
    const float* W1    = (const float*)d_in[6];
    const float* b1    = (const float*)d_in[7];
    const float* W2    = (const float*)d_in[8];
    const float* b2    = (const float*)d_in[9];
    const float* lng   = (const float*)d_in[10];
    const float* lnb   = (const float*)d_in[11];
    float* h32 = (float*)d_out;

    const int n = in_sizes[0] / HIDDEN;
    const int E = in_sizes[2] / 2;
    const int* src = ei;
    const int* dst = ei + E;

    size_t off = 0;
    auto take = [&](size_t bytes) {
        void* p = (char*)d_ws + off;
        off += (bytes + 255) & ~(size_t)255;
        return p;
    };
    ushort* z0p     = (ushort*)take((size_t)n * HIDDEN * 2);
    ushort* h16p    = (ushort*)take((size_t)(n + 1) * HIDDEN * 2);   // +1 sentinel row
    ushort* Wt      = (ushort*)take((size_t)NLAYERS * 2 * HIDDEN * HIDDEN * 2);
    ushort* WecolX  = (ushort*)take((size_t)HIDDEN * 32 * 2);
    int*    counts  = (int*)take((size_t)n * 4);
    int*    offsets = (int*)take(((size_t)n + 1) * 4);
    int*    wpos    = (int*)take((size_t)n * 4);
    int*    csr_src = (int*)take((size_t)E * 4);
    ushort* eattr16 = (ushort*)take((size_t)E * 16 * 2);

    const int prep_total = n * 16 + NLAYERS * 2 * HIDDEN * HIDDEN + 128 * 32 + 16;
    prep_kernel<<<(prep_total + 255) / 256, 256, 0, stream>>>(x, h16p, W1, W2, Wt,
                                                              We, be, WecolX, n);

    hipMemsetAsync(counts, 0, (size_t)n * 4, stream);
    int eb = (E + 255) / 256;
    hist_kernel<<<eb, 256, 0, stream>>>(dst, counts, E);
    scan_kernel<<<1, 1024, 0, stream>>>(counts, offsets, wpos, n);
    fill_kernel<<<eb, 256, 0, stream>>>(src, dst, wpos, csr_src,
                                        (const float4*)eattr, eattr16, E);

    for (int lyr = 0; lyr < NLAYERS; ++lyr) {
        agg_kernel<<<(n + 7) / 8, 256, 0, stream>>>(h16p, csr_src, eattr16, offsets,
                                                    WecolX, z0p, n);
        mlp_kernel<<<(n + 63) / 64, 256, 0, stream>>>(z0p, h16p, h32,
                                                      Wt + (size_t)(lyr * 2 + 0) * 16384,
                                                      Wt + (size_t)(lyr * 2 + 1) * 16384,
                                                      b1 + (size_t)lyr * HIDDEN,
                                                      b2 + (size_t)lyr * HIDDEN,
                                                      lng + (size_t)lyr * HIDDEN,
                                                      lnb + (size_t)lyr * HIDDEN,
                                                      n, lyr == NLAYERS - 1);
    }
}

// Round 15
// 352.648 us; speedup vs baseline: 1.5872x; 1.1364x over previous
//
#include <hip/hip_runtime.h>

#define HIDDEN 128
#define NLAYERS 4

typedef __attribute__((ext_vector_type(8))) short short8;
typedef __attribute__((ext_vector_type(4))) float f32x4;

__device__ __forceinline__ ushort f2bf(float f) {
    uint x = __builtin_bit_cast(uint, f);
    return (ushort)((x + 0x7fffu + ((x >> 16) & 1u)) >> 16);
}
__device__ __forceinline__ float bflo(uint u) {
    return __builtin_bit_cast(float, u << 16);
}
__device__ __forceinline__ float bfhi(uint u) {
    return __builtin_bit_cast(float, u & 0xffff0000u);
}

// ---------------- CSR build ----------------

__global__ void hist_kernel(const int* __restrict__ dst, int* __restrict__ counts, int E) {
    int e = blockIdx.x * blockDim.x + threadIdx.x;
    if (e < E) atomicAdd(&counts[dst[e]], 1);
}

// single-block scan, 4 elements/thread (4096/chunk)
__global__ __launch_bounds__(1024) void scan_kernel(const int* __restrict__ counts,
                                                    int* __restrict__ offsets,
                                                    int* __restrict__ wpos, int n) {
    __shared__ int wsum[16];
    __shared__ int carry_s;
    const int t = threadIdx.x, wv = t >> 6, ln = t & 63;
    if (t == 0) carry_s = 0;
    __syncthreads();
    for (int base = 0; base < n; base += 4096) {
        const int i = base + t * 4;
        int4 c = {0, 0, 0, 0};
        if (i + 3 < n) {
            c = *(const int4*)(counts + i);
        } else {
            if (i < n)     c.x = counts[i];
            if (i + 1 < n) c.y = counts[i + 1];
            if (i + 2 < n) c.z = counts[i + 2];
            if (i + 3 < n) c.w = counts[i + 3];
        }
        const int tsum = c.x + c.y + c.z + c.w;
        int s = tsum;
#pragma unroll
        for (int off = 1; off < 64; off <<= 1) {
            int x = __shfl_up(s, off, 64);
            if (ln >= off) s += x;
        }
        if (ln == 63) wsum[wv] = s;
        __syncthreads();
        if (t < 16) {
            int x = wsum[t];
#pragma unroll
            for (int off = 1; off < 16; off <<= 1) {
                int y = __shfl_up(x, off, 16);
                if ((t & 15) >= off) x += y;
            }
            wsum[t] = x;
        }
        __syncthreads();
        const int wbase = (wv ? wsum[wv - 1] : 0) + carry_s;
        const int excl = wbase + s - tsum;
        int4 o;
        o.x = excl;
        o.y = excl + c.x;
        o.z = o.y + c.y;
        o.w = o.z + c.z;
        if (i + 3 < n) {
            *(int4*)(offsets + i) = o;
            *(int4*)(wpos + i) = o;
        } else {
            if (i < n)     { offsets[i] = o.x;     wpos[i] = o.x; }
            if (i + 1 < n) { offsets[i + 1] = o.y; wpos[i + 1] = o.y; }
            if (i + 2 < n) { offsets[i + 2] = o.z; wpos[i + 2] = o.z; }
            if (i + 3 < n) { offsets[i + 3] = o.w; wpos[i + 3] = o.w; }
        }
        __syncthreads();
        if (t == 0) carry_s += wsum[15];
        __syncthreads();
    }
    if (t == 0) offsets[n] = carry_s;
}

// fill + eattr16 reorder fused: csr_src[p] = src[e]; eattr16[p][:] = bf16(edge_attr[e][:])
__global__ void fill_kernel(const int* __restrict__ src, const int* __restrict__ dst,
                            int* __restrict__ wpos, int* __restrict__ csr_src,
                            const float4* __restrict__ edge_attr,
                            ushort* __restrict__ eattr16, int E) {
    int e = blockIdx.x * blockDim.x + threadIdx.x;
    if (e < E) {
        int d = dst[e];
        int p = atomicAdd(&wpos[d], 1);
        csr_src[p] = src[e];
        float4 v0 = edge_attr[(size_t)e * 4 + 0];
        float4 v1 = edge_attr[(size_t)e * 4 + 1];
        float4 v2 = edge_attr[(size_t)e * 4 + 2];
        float4 v3 = edge_attr[(size_t)e * 4 + 3];
        uint4 q0, q1;
        q0.x = (uint)f2bf(v0.x) | ((uint)f2bf(v0.y) << 16);
        q0.y = (uint)f2bf(v0.z) | ((uint)f2bf(v0.w) << 16);
        q0.z = (uint)f2bf(v1.x) | ((uint)f2bf(v1.y) << 16);
        q0.w = (uint)f2bf(v1.z) | ((uint)f2bf(v1.w) << 16);
        q1.x = (uint)f2bf(v2.x) | ((uint)f2bf(v2.y) << 16);
        q1.y = (uint)f2bf(v2.z) | ((uint)f2bf(v2.w) << 16);
        q1.z = (uint)f2bf(v3.x) | ((uint)f2bf(v3.y) << 16);
        q1.w = (uint)f2bf(v3.z) | ((uint)f2bf(v3.w) << 16);
        ushort* op = eattr16 + (size_t)p * 16;
        *(uint4*)(op) = q0;
        *(uint4*)(op + 8) = q1;
    }
}

// ---------------- fused prep: h16init | wconv | wecolx (region-split) ----------------
// region A [0, n*16): h16p[row][pos], pos(ch) = (ch&15)*8 + (ch>>4)
// region B: Wt[(l*2+m)][nn][kpos]; m==0 K-rows permuted
// region C: WecolX[ch][k]: k<16 -> We[k][ch]; k==16 -> be[ch]; else 0
__global__ void prep_kernel(const float* __restrict__ x, ushort* __restrict__ h16p,
                            const float* __restrict__ W1, const float* __restrict__ W2,
                            ushort* __restrict__ Wt,
                            const float* __restrict__ We, const float* __restrict__ be,
                            ushort* __restrict__ WecolX, int n) {
    int i = blockIdx.x * blockDim.x + threadIdx.x;
    const int na = n * 16;
    if (i < na) {
        int row = i >> 4, lm = i & 15;
        const float* xp = x + (size_t)row * HIDDEN + lm;
        uint4 o;
        o.x = (uint)f2bf(xp[0])  | ((uint)f2bf(xp[16]) << 16);
        o.y = (uint)f2bf(xp[32]) | ((uint)f2bf(xp[48]) << 16);
        o.z = (uint)f2bf(xp[64]) | ((uint)f2bf(xp[80]) << 16);
        o.w = (uint)f2bf(xp[96]) | ((uint)f2bf(xp[112]) << 16);
        *(uint4*)(h16p + (size_t)row * HIDDEN + lm * 8) = o;
        return;
    }
    i -= na;
    if (i < NLAYERS * 2 * HIDDEN * HIDDEN) {
        int l = i >> 15;
        int m = (i >> 14) & 1;
        int nn = (i >> 7) & 127;
        int kpos = i & 127;
        int kk = (m == 0) ? (((kpos & 7) << 4) | (kpos >> 3)) : kpos;
        const float* W = m ? W2 : W1;
        Wt[i] = f2bf(W[l * 16384 + kk * 128 + nn]);
        return;
    }
    i -= NLAYERS * 2 * HIDDEN * HIDDEN;
    if (i < 128 * 32) {
        int ch = i >> 5, k = i & 31;
        float v = (k < 16) ? We[k * HIDDEN + ch] : ((k == 16) ? be[ch] : 0.f);
        WecolX[i] = f2bf(v);
    }
}

// ---------------- aggregation: MFMA ea recompute, zero LDS, 2 nodes/wave ----------------
// per 16-edge chunk:
//   A: rows=edges, K0-15=feats, K16=1.0 (lg==2 literal) -> be folded via B row 16 (WecolX)
//   B: resident frags (32 VGPR), loaded once per wave (amortized over 2 nodes)
//   D lane (lm,lg): edges lg*4+j, channels {nt*16+lm} == h16p gather positions lm*8+nt
__global__ __launch_bounds__(256) void agg_kernel(const ushort* __restrict__ h16p,
                                                  const int* __restrict__ csr_src,
                                                  const ushort* __restrict__ eattr16,
                                                  const int* __restrict__ offsets,
                                                  const ushort* __restrict__ WecolX,
                                                  ushort* __restrict__ z0p, int n) {
    const int w = threadIdx.x >> 6, l = threadIdx.x & 63;
    const int lm = l & 15, lg = l >> 4;

    // resident B-frags: lane covers K slots lg*8..+8 of channel nt*16+lm
    short8 bfr[8];
#pragma unroll
    for (int nt = 0; nt < 8; ++nt)
        bfr[nt] = *(const short8*)(WecolX + (size_t)(nt * 16 + lm) * 32 + lg * 8);

    for (int rep = 0; rep < 2; ++rep) {
        const int v = blockIdx.x * 8 + w + rep * 4;
        if (v >= n) continue;

        const int e0 = offsets[v], e1 = offsets[v + 1];
        float acc[8];
#pragma unroll
        for (int i = 0; i < 8; ++i) acc[i] = 0.f;

        for (int B = e0; B < e1; B += 16) {
            // A-frag: lg<2 = edge feats; lg==2 = {1.0,...} (bias row); lg==3 = 0
            short8 af;
            if (lg < 2) {
                int ae = B + lm;
                if (ae >= e1) ae = e1 - 1;
                af = *(const short8*)(eattr16 + (size_t)ae * 16 + lg * 8);
            } else if (lg == 2) {
                af = short8{(short)0x3F80, 0, 0, 0, 0, 0, 0, 0};
            } else {
                af = short8{0, 0, 0, 0, 0, 0, 0, 0};
            }

            // my group's 4 edges: mask + src + gathers (issued before MFMAs)
            float vm[4];
            int sj[4];
#pragma unroll
            for (int j = 0; j < 4; ++j) {
                int e = B + lg * 4 + j;
                vm[j] = (e < e1) ? 1.f : 0.f;
                int ec = (e < e1) ? e : (e1 - 1);
                sj[j] = csr_src[ec];
            }
            uint4 hv[4];
#pragma unroll
            for (int j = 0; j < 4; ++j)
                hv[j] = *(const uint4*)(h16p + (size_t)sj[j] * HIDDEN + lm * 8);

            // 8 channel tiles
#pragma unroll
            for (int nt = 0; nt < 8; ++nt) {
                f32x4 c = {0.f, 0.f, 0.f, 0.f};
                f32x4 d = __builtin_amdgcn_mfma_f32_16x16x32_bf16(af, bfr[nt], c, 0, 0, 0);
#pragma unroll
                for (int j = 0; j < 4; ++j) {
                    uint word = (nt < 2) ? hv[j].x : (nt < 4) ? hv[j].y
                              : (nt < 6) ? hv[j].z : hv[j].w;
                    float hc = (nt & 1) ? bfhi(word) : bflo(word);
                    acc[nt] = fmaf(vm[j], fmaxf(d[j] + hc, 0.f), acc[nt]);
                }
            }
        }

        // reduce across the 4 groups
#pragma unroll
        for (int i = 0; i < 8; ++i) {
            acc[i] += __shfl_xor(acc[i], 16, 64);
            acc[i] += __shfl_xor(acc[i], 32, 64);
        }

        if (lg == 0) {
            // self term from h16p (bf16 h), same permuted positions
            const uint4 sv = *(const uint4*)(h16p + (size_t)v * HIDDEN + lm * 8);
            uint4 o;
            o.x = (uint)f2bf(bflo(sv.x) + acc[0]) | ((uint)f2bf(bfhi(sv.x) + acc[1]) << 16);
            o.y = (uint)f2bf(bflo(sv.y) + acc[2]) | ((uint)f2bf(bfhi(sv.y) + acc[3]) << 16);
            o.z = (uint)f2bf(bflo(sv.z) + acc[4]) | ((uint)f2bf(bfhi(sv.z) + acc[5]) << 16);
            o.w = (uint)f2bf(bflo(sv.w) + acc[6]) | ((uint)f2bf(bfhi(sv.w) + acc[7]) << 16);
            *(uint4*)(z0p + (size_t)v * HIDDEN + lm * 8) = o;
        }
    }
}

// ---------------- fused MFMA MLP + in-register LayerNorm + bf16 residual ----------------
// z0p/h16p are channel-permuted; W1t has matching K-permutation.
// last==0: h16p <- bf16(relu(LN) + h16p). last==1: h32 <- relu(LN) + h16p (canonical layout).
__global__ __launch_bounds__(256, 3) void mlp_kernel(const ushort* __restrict__ z0p,
                                                     ushort* __restrict__ h16p,
                                                     float* __restrict__ h32,
                                                     const ushort* __restrict__ W1t,
                                                     const ushort* __restrict__ W2t,
                                                     const float* __restrict__ b1,
                                                     const float* __restrict__ b2,
                                                     const float* __restrict__ lng,
                                                     const float* __restrict__ lnb,
                                                     int n, int last) {
    __shared__ char smem[49152];  // [0,32K): weights (swizzled bf16) ; [32K,48K): act
    const int t = threadIdx.x, l = t & 63, w = t >> 6;
    const int lm = l & 15, lg = l >> 4;
    const int r0 = blockIdx.x * 64;

#pragma unroll
    for (int j = 0; j < 8; ++j) {
        int idx = t + j * 256;
        int byte = (idx * 16) ^ (((idx >> 4) & 7) << 4);
        *(short8*)(smem + byte) = *(const short8*)(W1t + idx * 8);
    }

    float b1v[8], b2v[8], lngv[8], lnbv[8];
#pragma unroll
    for (int nt = 0; nt < 8; ++nt) {
        int col = nt * 16 + lm;
        b1v[nt] = b1[col]; b2v[nt] = b2[col];
        lngv[nt] = lng[col]; lnbv[nt] = lnb[col];
    }

    short8 a[4];
    {
        int arow = r0 + w * 16 + lm;
        if (arow >= n) arow = n - 1;
        const ushort* zp = z0p + (size_t)arow * HIDDEN + lg * 8;
#pragma unroll
        for (int kk = 0; kk < 4; ++kk) a[kk] = *(const short8*)(zp + kk * 32);
    }
    __syncthreads();

    f32x4 acc[8];
#pragma unroll
    for (int nt = 0; nt < 8; ++nt) {
        f32x4 c = {0.f, 0.f, 0.f, 0.f};
#pragma unroll
        for (int kk = 0; kk < 4; ++kk) {
            int nrow = nt * 16 + lm;
            int byte = (nrow * 256 + kk * 64 + lg * 16) ^ ((nrow & 7) << 4);
            short8 b = *(const short8*)(smem + byte);
            c = __builtin_amdgcn_mfma_f32_16x16x32_bf16(a[kk], b, c, 0, 0, 0);
        }
        acc[nt] = c;
    }

#pragma unroll
    for (int nt = 0; nt < 8; ++nt) {
        int col = nt * 16 + lm;
#pragma unroll
        for (int j = 0; j < 4; ++j) {
            int rw = w * 16 + lg * 4 + j;
            int byte = (rw * 256 + col * 2) ^ ((rw & 7) << 4);
            *(ushort*)(smem + 32768 + byte) = f2bf(fmaxf(acc[nt][j] + b1v[nt], 0.f));
        }
    }
    __syncthreads();

#pragma unroll
    for (int j = 0; j < 8; ++j) {
        int idx = t + j * 256;
        int byte = (idx * 16) ^ (((idx >> 4) & 7) << 4);
        *(short8*)(smem + byte) = *(const short8*)(W2t + idx * 8);
    }
    short8 a2[4];
    {
        int rw = w * 16 + lm;
#pragma unroll
        for (int kk = 0; kk < 4; ++kk) {
            int byte = (rw * 256 + kk * 64 + lg * 16) ^ ((rw & 7) << 4);
            a2[kk] = *(const short8*)(smem + 32768 + byte);
        }
    }
    __syncthreads();

    f32x4 acc2[8];
#pragma unroll
    for (int nt = 0; nt < 8; ++nt) {
        f32x4 c = {0.f, 0.f, 0.f, 0.f};
#pragma unroll
        for (int kk = 0; kk < 4; ++kk) {
            int nrow = nt * 16 + lm;
            int byte = (nrow * 256 + kk * 64 + lg * 16) ^ ((nrow & 7) << 4);
            short8 b = *(const short8*)(smem + byte);
            c = __builtin_amdgcn_mfma_f32_16x16x32_bf16(a2[kk], b, c, 0, 0, 0);
        }
        acc2[nt] = c;
    }

    float val[8][4];
#pragma unroll
    for (int nt = 0; nt < 8; ++nt)
#pragma unroll
        for (int j = 0; j < 4; ++j) val[nt][j] = acc2[nt][j] + b2v[nt];

    float mu[4], rs[4];
#pragma unroll
    for (int j = 0; j < 4; ++j) {
        float s = 0.f;
#pragma unroll
        for (int nt = 0; nt < 8; ++nt) s += val[nt][j];
        s += __shfl_xor(s, 1, 64); s += __shfl_xor(s, 2, 64);
        s += __shfl_xor(s, 4, 64); s += __shfl_xor(s, 8, 64);
        mu[j] = s * (1.f / 128.f);
        float d2 = 0.f;
#pragma unroll
        for (int nt = 0; nt < 8; ++nt) {
            float d = val[nt][j] - mu[j];
            d2 = fmaf(d, d, d2);
        }
        d2 += __shfl_xor(d2, 1, 64); d2 += __shfl_xor(d2, 2, 64);
        d2 += __shfl_xor(d2, 4, 64); d2 += __shfl_xor(d2, 8, 64);
        rs[j] = rsqrtf(d2 * (1.f / 128.f) + 1e-5f);
    }

#pragma unroll
    for (int j = 0; j < 4; ++j) {
        int grow = r0 + w * 16 + lg * 4 + j;
        if (grow < n) {
            const uint4 hvv = *(const uint4*)(h16p + (size_t)grow * HIDDEN + lm * 8);
            float hc[8] = {bflo(hvv.x), bfhi(hvv.x), bflo(hvv.y), bfhi(hvv.y),
                           bflo(hvv.z), bfhi(hvv.z), bflo(hvv.w), bfhi(hvv.w)};
            float y[8];
#pragma unroll
            for (int nt = 0; nt < 8; ++nt)
                y[nt] = fmaxf((val[nt][j] - mu[j]) * rs[j] * lngv[nt] + lnbv[nt], 0.f) + hc[nt];
            if (last) {
#pragma unroll
                for (int nt = 0; nt < 8; ++nt)
                    h32[(size_t)grow * HIDDEN + nt * 16 + lm] = y[nt];
            } else {
                uint4 o4;
                o4.x = (uint)f2bf(y[0]) | ((uint)f2bf(y[1]) << 16);
                o4.y = (uint)f2bf(y[2]) | ((uint)f2bf(y[3]) << 16);
                o4.z = (uint)f2bf(y[4]) | ((uint)f2bf(y[5]) << 16);
                o4.w = (uint)f2bf(y[6]) | ((uint)f2bf(y[7]) << 16);
                *(uint4*)(h16p + (size_t)grow * HIDDEN + lm * 8) = o4;
            }
        }
    }
}

// ---------------- launch ----------------

extern "C" void kernel_launch(void* const* d_in, const int* in_sizes, int n_in,
                              void* d_out, int out_size, void* d_ws, size_t ws_size,
                              hipStream_t stream) {
    const float* x     = (const float*)d_in[0];
    const int*   ei    = (const int*)d_in[2];
    const float* eattr = (const float*)d_in[3];
    const float* We    = (const float*)d_in[4];
    const float* be    = (const float*)d_in[5];
    const float* W1    = (const float*)d_in[6];
    const float* b1    = (const float*)d_in[7];
    const float* W2    = (const float*)d_in[8];
    const float* b2    = (const float*)d_in[9];
    const float* lng   = (const float*)d_in[10];
    const float* lnb   = (const float*)d_in[11];
    float* h32 = (float*)d_out;

    const int n = in_sizes[0] / HIDDEN;
    const int E = in_sizes[2] / 2;
    const int* src = ei;
    const int* dst = ei + E;

    size_t off = 0;
    auto take = [&](size_t bytes) {
        void* p = (char*)d_ws + off;
        off += (bytes + 255) & ~(size_t)255;
        return p;
    };
    ushort* z0p     = (ushort*)take((size_t)n * HIDDEN * 2);
    ushort* h16p    = (ushort*)take((size_t)n * HIDDEN * 2);
    ushort* Wt      = (ushort*)take((size_t)NLAYERS * 2 * HIDDEN * HIDDEN * 2);
    ushort* WecolX  = (ushort*)take((size_t)HIDDEN * 32 * 2);
    int*    counts  = (int*)take((size_t)n * 4);
    int*    offsets = (int*)take(((size_t)n + 1) * 4);
    int*    wpos    = (int*)take((size_t)n * 4);
    int*    csr_src = (int*)take((size_t)E * 4);
    ushort* eattr16 = (ushort*)take((size_t)E * 16 * 2);

    const int prep_total = n * 16 + NLAYERS * 2 * HIDDEN * HIDDEN + 128 * 32;
    prep_kernel<<<(prep_total + 255) / 256, 256, 0, stream>>>(x, h16p, W1, W2, Wt,
                                                              We, be, WecolX, n);

    hipMemsetAsync(counts, 0, (size_t)n * 4, stream);
    int eb = (E + 255) / 256;
    hist_kernel<<<eb, 256, 0, stream>>>(dst, counts, E);
    scan_kernel<<<1, 1024, 0, stream>>>(counts, offsets, wpos, n);
    fill_kernel<<<eb, 256, 0, stream>>>(src, dst, wpos, csr_src,
                                        (const float4*)eattr, eattr16, E);

    for (int lyr = 0; lyr < NLAYERS; ++lyr) {
        agg_kernel<<<(n + 7) / 8, 256, 0, stream>>>(h16p, csr_src, eattr16, offsets,
                                                    WecolX, z0p, n);
        mlp_kernel<<<(n + 63) / 64, 256, 0, stream>>>(z0p, h16p, h32,
                                                      Wt + (size_t)(lyr * 2 + 0) * 16384,
                                                      Wt + (size_t)(lyr * 2 + 1) * 16384,
                                                      b1 + (size_t)lyr * HIDDEN,
                                                      b2 + (size_t)lyr * HIDDEN,
                                                      lng + (size_t)lyr * HIDDEN,
                                                      lnb + (size_t)lyr * HIDDEN,
                                                      n, lyr == NLAYERS - 1);
    }
}